// Round 5
// baseline (657.367 us; speedup 1.0000x reference)
//
#include <hip/hip_runtime.h>
#include <hip/hip_bf16.h>

// Performer (FAVOR+) causal attention, fp32.
// B=2 H=16 L=2048 D=64 M=256. Chunked linear attention:
//   K1: global max of h_of_k (k_stab)
//   K2: per-chunk S = K'^T V (MxD) and z = colsum(K'), on-the-fly k'
//   K3: exclusive prefix of S,z over chunks (in-place)
//   K4: per-chunk output: inter (Q'@S_prev) + intra causal (Q'K'^T masked @ V),
//       denom via identity den[l] = q'_l.zprev + sum_{j<=l} A[l][j]  (A reused),
//       S updated in LDS per 32-row sub-tile.
// R2: register-prefetch staging (T14) in K2/K4; wave-uniform predicated intra loop.
// R3: den-from-A restructure (removes 192 shfl + 32 LDS atomics per thread/sub-tile).
// R4: contiguous-m S-update ownership: KPl reads 16x ds_read_b32 -> 4x ds_read_b128
//     per l (512->128 LDS insts/thread/sub-tile) in K2 and K4. S layout unchanged.
// ws layout: [0..4) umax | [1KB..) Z (512KB) | [1KB+512KB..) S (32MB)  => ~34.1MB

#define Lc    2048
#define Dc    64
#define Mc    256
#define CHUNK 128
#define NCH   16
#define NBLK  512            // B*H*NCH = 32*16
#define S_SCALE 0.17677669529663687f   // 1024^-0.25
#define S2_     0.03125f               // S_SCALE^2
#define NC_     0.0625f                // 256^-0.5
#define EPS_    1e-6f

__device__ __forceinline__ float dec_max(const unsigned* p){
  unsigned u = *p;
  unsigned b = (u & 0x80000000u) ? (u & 0x7fffffffu) : ~u;
  return __uint_as_float(b);
}

// ---------------- K1: global max of h_of_k ----------------
__global__ void hmax_kernel(const float* __restrict__ k_g, unsigned* __restrict__ umax){
  size_t row = (size_t)blockIdx.x * 256 + threadIdx.x;   // 65536 rows
  const float4* kr = (const float4*)(k_g + row * Dc);
  float sq = 0.f;
  #pragma unroll
  for (int i = 0; i < 16; ++i){
    float4 v = kr[i];
    sq += v.x*v.x + v.y*v.y + v.z*v.z + v.w*v.w;
  }
  float h = -0.5f * S2_ * sq;
  #pragma unroll
  for (int o = 32; o; o >>= 1) h = fmaxf(h, __shfl_xor(h, o));
  if ((threadIdx.x & 63) == 0){
    unsigned b = __float_as_uint(h);
    b = (b & 0x80000000u) ? ~b : (b | 0x80000000u);
    atomicMax(umax, b);
  }
}

// ---------------- K2: per-chunk S, z sums ----------------
__launch_bounds__(256, 2)
__global__ void chunk_kernel(const float* __restrict__ k_g, const float* __restrict__ v_g,
                             const float* __restrict__ rf, const unsigned* __restrict__ umax,
                             float* __restrict__ Sws, float* __restrict__ Zws){
  __shared__ float Kst[2048];
  __shared__ float Vl[2048];
  __shared__ float KPl[32*260];
  __shared__ float hks[32];
  const int bid = blockIdx.x, t = threadIdx.x;
  const int dq = t & 15, mg = t >> 4;
  float rfc[64];
  #pragma unroll
  for (int d = 0; d < 64; ++d) rfc[d] = rf[d*Mc + t];
  const float kmax = dec_max(umax);
  const float* kb = k_g + (size_t)bid * CHUNK * Dc;
  const float* vb = v_g + (size_t)bid * CHUNK * Dc;
  float4 sacc[16];   // sacc[mi] accumulates S row m = mg*16 + mi (contiguous block)
  #pragma unroll
  for (int i = 0; i < 16; ++i) sacc[i] = make_float4(0.f,0.f,0.f,0.f);
  float zacc = 0.f;

  // prefetch st=0
  float4 kr0, kr1, vr0, vr1;
  {
    const float4* ks = (const float4*)kb;
    const float4* vs = (const float4*)vb;
    kr0 = ks[t]; kr1 = ks[256 + t];
    vr0 = vs[t]; vr1 = vs[256 + t];
  }

  for (int st = 0; st < 4; ++st){
    __syncthreads();   // protect Kst/Vl/KPl vs previous iteration's readers
    { // write staged K,V; hks from registers
      ((float4*)Kst)[t] = kr0; ((float4*)Kst)[256 + t] = kr1;
      ((float4*)Vl)[t]  = vr0; ((float4*)Vl)[256 + t]  = vr1;
      float p0 = kr0.x*kr0.x + kr0.y*kr0.y + kr0.z*kr0.z + kr0.w*kr0.w;
      p0 += __shfl_xor(p0, 8); p0 += __shfl_xor(p0, 4);
      p0 += __shfl_xor(p0, 2); p0 += __shfl_xor(p0, 1);
      float p1 = kr1.x*kr1.x + kr1.y*kr1.y + kr1.z*kr1.z + kr1.w*kr1.w;
      p1 += __shfl_xor(p1, 8); p1 += __shfl_xor(p1, 4);
      p1 += __shfl_xor(p1, 2); p1 += __shfl_xor(p1, 1);
      if ((t & 15) == 0){
        hks[t >> 4]        = -0.5f * S2_ * p0;
        hks[(256+t) >> 4]  = -0.5f * S2_ * p1;
      }
    }
    __syncthreads();
    // issue next-subtile loads (latency hides under kfeat below)
    if (st < 3){
      const float4* ks = (const float4*)(kb + (st+1)*32*Dc);
      const float4* vs = (const float4*)(vb + (st+1)*32*Dc);
      kr0 = ks[t]; kr1 = ks[256 + t];
      vr0 = vs[t]; vr1 = vs[256 + t];
    }
    #pragma unroll 1
    for (int l = 0; l < 32; ++l){
      float pk = 0.f;
      #pragma unroll
      for (int i = 0; i < 16; ++i){
        float4 kv = ((const float4*)Kst)[l*16 + i];
        pk += kv.x*rfc[4*i] + kv.y*rfc[4*i+1] + kv.z*rfc[4*i+2] + kv.w*rfc[4*i+3];
      }
      float kp = NC_ * (__expf(hks[l] + S_SCALE*pk - kmax) + EPS_);
      KPl[l*260 + t] = kp;
      zacc += kp;
    }
    __syncthreads();
    #pragma unroll 2
    for (int l = 0; l < 32; ++l){
      const float4 vv = ((const float4*)Vl)[l*16 + dq];
      const float* kpr = &KPl[l*260 + mg*16];
      #pragma unroll
      for (int i = 0; i < 4; ++i){
        const float4 kp4 = *(const float4*)&kpr[4*i];
        sacc[4*i  ].x += kp4.x*vv.x; sacc[4*i  ].y += kp4.x*vv.y;
        sacc[4*i  ].z += kp4.x*vv.z; sacc[4*i  ].w += kp4.x*vv.w;
        sacc[4*i+1].x += kp4.y*vv.x; sacc[4*i+1].y += kp4.y*vv.y;
        sacc[4*i+1].z += kp4.y*vv.z; sacc[4*i+1].w += kp4.y*vv.w;
        sacc[4*i+2].x += kp4.z*vv.x; sacc[4*i+2].y += kp4.z*vv.y;
        sacc[4*i+2].z += kp4.z*vv.z; sacc[4*i+2].w += kp4.z*vv.w;
        sacc[4*i+3].x += kp4.w*vv.x; sacc[4*i+3].y += kp4.w*vv.y;
        sacc[4*i+3].z += kp4.w*vv.z; sacc[4*i+3].w += kp4.w*vv.w;
      }
    }
  }
  Zws[(size_t)bid*Mc + t] = zacc;
  float4* sd = (float4*)(Sws + (size_t)bid*Mc*Dc);
  #pragma unroll
  for (int mi = 0; mi < 16; ++mi) sd[(mg*16 + mi)*16 + dq] = sacc[mi];
}

// ---------------- K3: exclusive prefix over chunks ----------------
__global__ void prefix_kernel(float* __restrict__ Sws, float* __restrict__ Zws){
  const int bh = blockIdx.x >> 4, sl = blockIdx.x & 15;
  const int t = threadIdx.x;
  float run[4] = {0.f, 0.f, 0.f, 0.f};
  size_t base = (size_t)bh * NCH * Mc * Dc + (size_t)sl * 1024;
  for (int c = 0; c < NCH; ++c){
    float* p = Sws + base + (size_t)c * Mc * Dc;
    #pragma unroll
    for (int r = 0; r < 4; ++r){
      float tmp = p[r*256 + t];
      p[r*256 + t] = run[r];
      run[r] += tmp;
    }
  }
  if (sl == 0){
    float zr = 0.f;
    for (int c = 0; c < NCH; ++c){
      float* z = Zws + ((size_t)bh*NCH + c) * Mc;
      float tmp = z[t];
      z[t] = zr;
      zr += tmp;
    }
  }
}

// ---------------- K4: outputs ----------------
// KPl has 33 rows: rows 0..31 = k' block, row 32 = zprev (exclusive cumsum of k').
#define OUT_LDS_FLOATS (16384 + 8320 + 8580 + 2048 + 2048 + 1056 + 128 + 32)
#define OUT_LDS_BYTES  (OUT_LDS_FLOATS * 4)

__launch_bounds__(256, 1)
__global__ void out_kernel(const float* __restrict__ q_g, const float* __restrict__ k_g,
                           const float* __restrict__ v_g, const float* __restrict__ rf,
                           const unsigned* __restrict__ umax,
                           const float* __restrict__ Sws, const float* __restrict__ Zws,
                           float* __restrict__ out){
  extern __shared__ float sm[];
  float* S_lds = sm;                 // [256][64]
  float* QPl   = S_lds + 16384;      // [32][260]
  float* KPl   = QPl + 8320;         // [33][260] (row 32 = zprev)
  float* Vl    = KPl + 8580;         // [32][64]
  float* QKst  = Vl + 2048;          // [32][64] staging (Q then K)
  float* Al    = QKst + 2048;        // [32][33]
  float* den   = Al + 1056;          // [128]
  float* hks   = den + 128;          // [32]

  const int bid = blockIdx.x, t = threadIdx.x;
  const int dq = t & 15, lh = t >> 4;     // output / inter mapping
  const int jc = t & 15, rp = t >> 4;     // A 2x2 mapping: rows {rp,rp+16}, cols {jc,jc+16}
  const int dl = t >> 3, dm = t & 7;      // den mapping: 8 threads per row dl

  const float* qb = q_g + (size_t)bid * CHUNK * Dc;
  const float* kb = k_g + (size_t)bid * CHUNK * Dc;
  const float* vb = v_g + (size_t)bid * CHUNK * Dc;

  // prefetch st=0 Q,K,V first (longest-latency consumers come first)
  float4 qr0, qr1, kr0, kr1, vr0, vr1;
  {
    const float4* qs = (const float4*)qb;
    const float4* ks = (const float4*)kb;
    const float4* vs = (const float4*)vb;
    qr0 = qs[t]; qr1 = qs[256 + t];
    kr0 = ks[t]; kr1 = ks[256 + t];
    vr0 = vs[t]; vr1 = vs[256 + t];
  }

  float rfc[64];
  #pragma unroll
  for (int d = 0; d < 64; ++d) rfc[d] = rf[d*Mc + t];
  const float kmax = dec_max(umax);

  { // stage S_prev
    const float4* s4 = (const float4*)(Sws + (size_t)bid*Mc*Dc);
    float4* d4 = (float4*)S_lds;
    #pragma unroll
    for (int r = 0; r < 16; ++r) d4[r*256 + t] = s4[r*256 + t];
  }
  float zreg = Zws[(size_t)bid*Mc + t];   // zprev for sub-tile 0

  float4 acc[8];
  #pragma unroll
  for (int i = 0; i < 8; ++i) acc[i] = make_float4(0.f,0.f,0.f,0.f);
  __syncthreads();

  for (int st = 0; st < 4; ++st){
    { // phase A: write staged Q and V; hks from in-register K
      float4* d4 = (float4*)QKst;
      d4[t] = qr0; d4[256 + t] = qr1;
      float4* v4 = (float4*)Vl;
      v4[t] = vr0; v4[256 + t] = vr1;
      float p0 = kr0.x*kr0.x + kr0.y*kr0.y + kr0.z*kr0.z + kr0.w*kr0.w;
      p0 += __shfl_xor(p0, 8); p0 += __shfl_xor(p0, 4);
      p0 += __shfl_xor(p0, 2); p0 += __shfl_xor(p0, 1);
      float p1 = kr1.x*kr1.x + kr1.y*kr1.y + kr1.z*kr1.z + kr1.w*kr1.w;
      p1 += __shfl_xor(p1, 8); p1 += __shfl_xor(p1, 4);
      p1 += __shfl_xor(p1, 2); p1 += __shfl_xor(p1, 1);
      if ((t & 15) == 0){
        hks[t >> 4]       = -0.5f * S2_ * p0;
        hks[(256+t) >> 4] = -0.5f * S2_ * p1;
      }
    }
    __syncthreads();
    // phase B: q' columns (m = t); next Q,V loads hide under this
    if (st < 3){
      const float4* qs = (const float4*)(qb + (st+1)*32*Dc);
      const float4* vs = (const float4*)(vb + (st+1)*32*Dc);
      qr0 = qs[t]; qr1 = qs[256 + t];
      vr0 = vs[t]; vr1 = vs[256 + t];
    }
    #pragma unroll 1
    for (int l = 0; l < 32; ++l){
      float pq = 0.f;
      #pragma unroll
      for (int i = 0; i < 16; ++i){
        float4 qv = ((const float4*)QKst)[l*16 + i];
        pq += qv.x*rfc[4*i] + qv.y*rfc[4*i+1] + qv.z*rfc[4*i+2] + qv.w*rfc[4*i+3];
      }
      QPl[l*260 + t] = NC_ * (__expf(S_SCALE * pq) + EPS_);
    }
    __syncthreads();
    { // phase C: write staged K over QKst; publish zprev (pre-update zreg) as KPl row 32
      float4* d4 = (float4*)QKst;
      d4[t] = kr0; d4[256 + t] = kr1;
      KPl[32*260 + t] = zreg;
    }
    __syncthreads();
    // phase D: k' columns (pure per-thread now); next K loads hide under this
    if (st < 3){
      const float4* ks = (const float4*)(kb + (st+1)*32*Dc);
      kr0 = ks[t]; kr1 = ks[256 + t];
    }
    #pragma unroll 1
    for (int l = 0; l < 32; ++l){
      float pk = 0.f;
      #pragma unroll
      for (int i = 0; i < 16; ++i){
        float4 kv = ((const float4*)QKst)[l*16 + i];
        pk += kv.x*rfc[4*i] + kv.y*rfc[4*i+1] + kv.z*rfc[4*i+2] + kv.w*rfc[4*i+3];
      }
      float kp = NC_ * (__expf(hks[l] + S_SCALE*pk - kmax) + EPS_);
      KPl[l*260 + t] = kp;
      zreg += kp;   // inclusive cumsum; becomes zprev for next sub-tile
    }
    __syncthreads();
    { // A = Q' K'^T, 2x2 blocked: rows {rp, rp+16}, cols {jc, jc+16}
      float a00 = 0.f, a01 = 0.f, a10 = 0.f, a11 = 0.f;
      const float* q0 = &QPl[rp*260];
      const float* q1 = &QPl[(rp+16)*260];
      const float* k0 = &KPl[jc*260];
      const float* k1 = &KPl[(jc+16)*260];
      #pragma unroll 4
      for (int mq = 0; mq < 64; ++mq){
        const float4 kv0 = *(const float4*)&k0[4*mq];
        const float4 kv1 = *(const float4*)&k1[4*mq];
        const float4 qv0 = *(const float4*)&q0[4*mq];
        const float4 qv1 = *(const float4*)&q1[4*mq];
        a00 += qv0.x*kv0.x + qv0.y*kv0.y + qv0.z*kv0.z + qv0.w*kv0.w;
        a01 += qv0.x*kv1.x + qv0.y*kv1.y + qv0.z*kv1.z + qv0.w*kv1.w;
        a10 += qv1.x*kv0.x + qv1.y*kv0.y + qv1.z*kv0.z + qv1.w*kv0.w;
        a11 += qv1.x*kv1.x + qv1.y*kv1.y + qv1.z*kv1.z + qv1.w*kv1.w;
      }
      Al[(rp   )*33 + jc     ] = a00;
      Al[(rp   )*33 + jc + 16] = a01;
      Al[(rp+16)*33 + jc     ] = a10;
      Al[(rp+16)*33 + jc + 16] = a11;
    }
    __syncthreads();
    { // den[l] = q'_l . zprev + sum_{j<=l} A[l][j]; 8 threads per row dl
      float dsum = 0.f;
      const float* qrow = &QPl[dl*260 + dm*32];
      const float* zrow = &KPl[32*260 + dm*32];
      #pragma unroll
      for (int i = 0; i < 8; ++i){
        const float4 qv = *(const float4*)&qrow[4*i];
        const float4 zv = *(const float4*)&zrow[4*i];
        dsum += qv.x*zv.x + qv.y*zv.y + qv.z*zv.z + qv.w*zv.w;
      }
      const float* arow = &Al[dl*33 + dm*4];
      #pragma unroll
      for (int i = 0; i < 4; ++i){
        const int j = dm*4 + i;
        dsum += (j <= dl) ? arow[i] : 0.f;
      }
      dsum += __shfl_xor(dsum, 1);
      dsum += __shfl_xor(dsum, 2);
      dsum += __shfl_xor(dsum, 4);
      if (dm == 0) den[st*32 + dl] = dsum;
    }
    { // inter (Q' @ S_prev) fused over both rows (S read once per m), then intra
      float4 a0 = acc[st*2], a1 = acc[st*2+1];     // rows lh, lh+16
      const float* q0 = &QPl[lh*260];
      const float* q1 = &QPl[(lh+16)*260];
      #pragma unroll 4
      for (int mb = 0; mb < 64; ++mb){
        const float4 qa = *(const float4*)&q0[4*mb];
        const float4 qb4 = *(const float4*)&q1[4*mb];
        const float4 s0 = *(const float4*)&S_lds[(4*mb  )*64 + 4*dq];
        const float4 s1 = *(const float4*)&S_lds[(4*mb+1)*64 + 4*dq];
        const float4 s2 = *(const float4*)&S_lds[(4*mb+2)*64 + 4*dq];
        const float4 s3 = *(const float4*)&S_lds[(4*mb+3)*64 + 4*dq];
        a0.x += qa.x*s0.x + qa.y*s1.x + qa.z*s2.x + qa.w*s3.x;
        a0.y += qa.x*s0.y + qa.y*s1.y + qa.z*s2.y + qa.w*s3.y;
        a0.z += qa.x*s0.z + qa.y*s1.z + qa.z*s2.z + qa.w*s3.z;
        a0.w += qa.x*s0.w + qa.y*s1.w + qa.z*s2.w + qa.w*s3.w;
        a1.x += qb4.x*s0.x + qb4.y*s1.x + qb4.z*s2.x + qb4.w*s3.x;
        a1.y += qb4.x*s0.y + qb4.y*s1.y + qb4.z*s2.y + qb4.w*s3.y;
        a1.z += qb4.x*s0.z + qb4.y*s1.z + qb4.z*s2.z + qb4.w*s3.z;
        a1.w += qb4.x*s0.w + qb4.y*s1.w + qb4.z*s2.w + qb4.w*s3.w;
      }
      { // intra: wave-uniform trip, per-lane predication, shared Vl read
        const float* arow0 = &Al[lh*33];
        const float* arow1 = &Al[(lh+16)*33];
        const int jmax = (lh | 3) + 17;   // uniform within each wave
        #pragma unroll 2
        for (int j = 0; j < jmax; ++j){
          const float av0 = (j <= lh)      ? arow0[j] : 0.f;
          const float av1 = (j <= lh + 16) ? arow1[j] : 0.f;
          const float4 vv = ((const float4*)Vl)[j*16 + dq];
          a0.x += av0*vv.x; a0.y += av0*vv.y; a0.z += av0*vv.z; a0.w += av0*vv.w;
          a1.x += av1*vv.x; a1.y += av1*vv.y; a1.z += av1*vv.z; a1.w += av1*vv.w;
        }
      }
      acc[st*2] = a0; acc[st*2+1] = a1;
    }
    __syncthreads();
    { // S += K'^T V ; thread (mg,dq) owns contiguous rows m = mg*16..mg*16+15
      const int mg = t >> 4;
      float4 sacc[16];
      #pragma unroll
      for (int mi = 0; mi < 16; ++mi)
        sacc[mi] = *(const float4*)&S_lds[(mg*16 + mi)*64 + 4*dq];
      #pragma unroll 2
      for (int l = 0; l < 32; ++l){
        const float4 vv = ((const float4*)Vl)[l*16 + dq];
        const float* kpr = &KPl[l*260 + mg*16];
        #pragma unroll
        for (int i = 0; i < 4; ++i){
          const float4 kp4 = *(const float4*)&kpr[4*i];
          sacc[4*i  ].x += kp4.x*vv.x; sacc[4*i  ].y += kp4.x*vv.y;
          sacc[4*i  ].z += kp4.x*vv.z; sacc[4*i  ].w += kp4.x*vv.w;
          sacc[4*i+1].x += kp4.y*vv.x; sacc[4*i+1].y += kp4.y*vv.y;
          sacc[4*i+1].z += kp4.y*vv.z; sacc[4*i+1].w += kp4.y*vv.w;
          sacc[4*i+2].x += kp4.z*vv.x; sacc[4*i+2].y += kp4.z*vv.y;
          sacc[4*i+2].z += kp4.z*vv.z; sacc[4*i+2].w += kp4.z*vv.w;
          sacc[4*i+3].x += kp4.w*vv.x; sacc[4*i+3].y += kp4.w*vv.y;
          sacc[4*i+3].z += kp4.w*vv.z; sacc[4*i+3].w += kp4.w*vv.w;
        }
      }
      #pragma unroll
      for (int mi = 0; mi < 16; ++mi)
        *(float4*)&S_lds[(mg*16 + mi)*64 + 4*dq] = sacc[mi];
    }
    __syncthreads();
  }
  // write out (divide by denominator)
  float* ob = out + (size_t)bid * CHUNK * Dc;
  #pragma unroll
  for (int st = 0; st < 4; ++st){
    #pragma unroll
    for (int half = 0; half < 2; ++half){
      const int lrel = lh + 16*half;
      const float inv = 1.f / den[st*32 + lrel];
      float4 a = acc[st*2 + half];
      a.x *= inv; a.y *= inv; a.z *= inv; a.w *= inv;
      *(float4*)&ob[(st*32 + lrel)*Dc + 4*dq] = a;
    }
  }
}

extern "C" void kernel_launch(void* const* d_in, const int* in_sizes, int n_in,
                              void* d_out, int out_size, void* d_ws, size_t ws_size,
                              hipStream_t stream){
  const float* q  = (const float*)d_in[0];
  const float* k  = (const float*)d_in[1];
  const float* v  = (const float*)d_in[2];
  const float* rf = (const float*)d_in[3];
  float* out = (float*)d_out;

  unsigned* umax = (unsigned*)d_ws;
  float* Zws = (float*)((char*)d_ws + 1024);                  // 512 KB
  float* Sws = (float*)((char*)d_ws + 1024 + 512*1024);       // 32 MB
  // total ws needed ~ 34.1 MB

  hipMemsetAsync(d_ws, 0, 4, stream);   // umax = encoded identity (below all real h values)
  hmax_kernel <<<256, 256, 0, stream>>>(k, umax);
  chunk_kernel<<<NBLK, 256, 0, stream>>>(k, v, rf, umax, Sws, Zws);
  prefix_kernel<<<NBLK, 256, 0, stream>>>(Sws, Zws);
  hipFuncSetAttribute((const void*)out_kernel,
                      hipFuncAttributeMaxDynamicSharedMemorySize, OUT_LDS_BYTES);
  out_kernel  <<<NBLK, 256, OUT_LDS_BYTES, stream>>>(q, k, v, rf, umax, Sws, Zws, out);
}

// Round 8
// 477.243 us; speedup vs baseline: 1.3774x; 1.3774x over previous
//
#include <hip/hip_runtime.h>
#include <hip/hip_bf16.h>

// Performer (FAVOR+) causal attention, fp32.
// B=2 H=16 L=2048 D=64 M=256. Chunked linear attention:
//   K1: global max of h_of_k (k_stab)
//   K2: per-chunk S = K'^T V (MxD) and z = colsum(K'), on-the-fly k'
//   K3: exclusive prefix of S,z over chunks (in-place)
//   K4: per-chunk output: inter (Q'@S_prev) + intra causal (Q'K'^T masked @ V),
//       denom via identity den[l] = q'_l.zprev + sum_{j<=l} A[l][j]  (A reused),
//       S updated in LDS per 32-row sub-tile.
// R5 counters: out_kernel 511us, VALUBusy 32%, Occupancy 11.8% (1 wave/SIMD) -> latency-bound.
// R6: out_kernel 256->512 threads (2 waves/SIMD, halves per-wave work in every phase);
//     den fully in-register (butterfly), per-subtile output store, acc[]/den[] deleted.
// R7/R8: resubmissions of R6 (benches never ran - GPU acquisition timeouts). No changes.
// ws layout: [0..4) umax | [1KB..) Z (512KB) | [1KB+512KB..) S (32MB)  => ~34.1MB

#define Lc    2048
#define Dc    64
#define Mc    256
#define CHUNK 128
#define NCH   16
#define NBLK  512            // B*H*NCH = 32*16
#define S_SCALE 0.17677669529663687f   // 1024^-0.25
#define S2_     0.03125f               // S_SCALE^2
#define NC_     0.0625f                // 256^-0.5
#define EPS_    1e-6f

__device__ __forceinline__ float dec_max(const unsigned* p){
  unsigned u = *p;
  unsigned b = (u & 0x80000000u) ? (u & 0x7fffffffu) : ~u;
  return __uint_as_float(b);
}

// ---------------- K1: global max of h_of_k ----------------
__global__ void hmax_kernel(const float* __restrict__ k_g, unsigned* __restrict__ umax){
  size_t row = (size_t)blockIdx.x * 256 + threadIdx.x;   // 65536 rows
  const float4* kr = (const float4*)(k_g + row * Dc);
  float sq = 0.f;
  #pragma unroll
  for (int i = 0; i < 16; ++i){
    float4 v = kr[i];
    sq += v.x*v.x + v.y*v.y + v.z*v.z + v.w*v.w;
  }
  float h = -0.5f * S2_ * sq;
  #pragma unroll
  for (int o = 32; o; o >>= 1) h = fmaxf(h, __shfl_xor(h, o));
  if ((threadIdx.x & 63) == 0){
    unsigned b = __float_as_uint(h);
    b = (b & 0x80000000u) ? ~b : (b | 0x80000000u);
    atomicMax(umax, b);
  }
}

// ---------------- K2: per-chunk S, z sums ----------------
__launch_bounds__(256, 2)
__global__ void chunk_kernel(const float* __restrict__ k_g, const float* __restrict__ v_g,
                             const float* __restrict__ rf, const unsigned* __restrict__ umax,
                             float* __restrict__ Sws, float* __restrict__ Zws){
  __shared__ float Kst[2048];
  __shared__ float Vl[2048];
  __shared__ float KPl[32*260];
  __shared__ float hks[32];
  const int bid = blockIdx.x, t = threadIdx.x;
  const int dq = t & 15, mg = t >> 4;
  float rfc[64];
  #pragma unroll
  for (int d = 0; d < 64; ++d) rfc[d] = rf[d*Mc + t];
  const float kmax = dec_max(umax);
  const float* kb = k_g + (size_t)bid * CHUNK * Dc;
  const float* vb = v_g + (size_t)bid * CHUNK * Dc;
  float4 sacc[16];   // sacc[mi] accumulates S row m = mg*16 + mi (contiguous block)
  #pragma unroll
  for (int i = 0; i < 16; ++i) sacc[i] = make_float4(0.f,0.f,0.f,0.f);
  float zacc = 0.f;

  // prefetch st=0
  float4 kr0, kr1, vr0, vr1;
  {
    const float4* ks = (const float4*)kb;
    const float4* vs = (const float4*)vb;
    kr0 = ks[t]; kr1 = ks[256 + t];
    vr0 = vs[t]; vr1 = vs[256 + t];
  }

  for (int st = 0; st < 4; ++st){
    __syncthreads();   // protect Kst/Vl/KPl vs previous iteration's readers
    { // write staged K,V; hks from registers
      ((float4*)Kst)[t] = kr0; ((float4*)Kst)[256 + t] = kr1;
      ((float4*)Vl)[t]  = vr0; ((float4*)Vl)[256 + t]  = vr1;
      float p0 = kr0.x*kr0.x + kr0.y*kr0.y + kr0.z*kr0.z + kr0.w*kr0.w;
      p0 += __shfl_xor(p0, 8); p0 += __shfl_xor(p0, 4);
      p0 += __shfl_xor(p0, 2); p0 += __shfl_xor(p0, 1);
      float p1 = kr1.x*kr1.x + kr1.y*kr1.y + kr1.z*kr1.z + kr1.w*kr1.w;
      p1 += __shfl_xor(p1, 8); p1 += __shfl_xor(p1, 4);
      p1 += __shfl_xor(p1, 2); p1 += __shfl_xor(p1, 1);
      if ((t & 15) == 0){
        hks[t >> 4]        = -0.5f * S2_ * p0;
        hks[(256+t) >> 4]  = -0.5f * S2_ * p1;
      }
    }
    __syncthreads();
    // issue next-subtile loads (latency hides under kfeat below)
    if (st < 3){
      const float4* ks = (const float4*)(kb + (st+1)*32*Dc);
      const float4* vs = (const float4*)(vb + (st+1)*32*Dc);
      kr0 = ks[t]; kr1 = ks[256 + t];
      vr0 = vs[t]; vr1 = vs[256 + t];
    }
    #pragma unroll 1
    for (int l = 0; l < 32; ++l){
      float pk = 0.f;
      #pragma unroll
      for (int i = 0; i < 16; ++i){
        float4 kv = ((const float4*)Kst)[l*16 + i];
        pk += kv.x*rfc[4*i] + kv.y*rfc[4*i+1] + kv.z*rfc[4*i+2] + kv.w*rfc[4*i+3];
      }
      float kp = NC_ * (__expf(hks[l] + S_SCALE*pk - kmax) + EPS_);
      KPl[l*260 + t] = kp;
      zacc += kp;
    }
    __syncthreads();
    #pragma unroll 2
    for (int l = 0; l < 32; ++l){
      const float4 vv = ((const float4*)Vl)[l*16 + dq];
      const float* kpr = &KPl[l*260 + mg*16];
      #pragma unroll
      for (int i = 0; i < 4; ++i){
        const float4 kp4 = *(const float4*)&kpr[4*i];
        sacc[4*i  ].x += kp4.x*vv.x; sacc[4*i  ].y += kp4.x*vv.y;
        sacc[4*i  ].z += kp4.x*vv.z; sacc[4*i  ].w += kp4.x*vv.w;
        sacc[4*i+1].x += kp4.y*vv.x; sacc[4*i+1].y += kp4.y*vv.y;
        sacc[4*i+1].z += kp4.y*vv.z; sacc[4*i+1].w += kp4.y*vv.w;
        sacc[4*i+2].x += kp4.z*vv.x; sacc[4*i+2].y += kp4.z*vv.y;
        sacc[4*i+2].z += kp4.z*vv.z; sacc[4*i+2].w += kp4.z*vv.w;
        sacc[4*i+3].x += kp4.w*vv.x; sacc[4*i+3].y += kp4.w*vv.y;
        sacc[4*i+3].z += kp4.w*vv.z; sacc[4*i+3].w += kp4.w*vv.w;
      }
    }
  }
  Zws[(size_t)bid*Mc + t] = zacc;
  float4* sd = (float4*)(Sws + (size_t)bid*Mc*Dc);
  #pragma unroll
  for (int mi = 0; mi < 16; ++mi) sd[(mg*16 + mi)*16 + dq] = sacc[mi];
}

// ---------------- K3: exclusive prefix over chunks ----------------
__global__ void prefix_kernel(float* __restrict__ Sws, float* __restrict__ Zws){
  const int bh = blockIdx.x >> 4, sl = blockIdx.x & 15;
  const int t = threadIdx.x;
  float run[4] = {0.f, 0.f, 0.f, 0.f};
  size_t base = (size_t)bh * NCH * Mc * Dc + (size_t)sl * 1024;
  for (int c = 0; c < NCH; ++c){
    float* p = Sws + base + (size_t)c * Mc * Dc;
    #pragma unroll
    for (int r = 0; r < 4; ++r){
      float tmp = p[r*256 + t];
      p[r*256 + t] = run[r];
      run[r] += tmp;
    }
  }
  if (sl == 0){
    float zr = 0.f;
    for (int c = 0; c < NCH; ++c){
      float* z = Zws + ((size_t)bh*NCH + c) * Mc;
      float tmp = z[t];
      z[t] = zr;
      zr += tmp;
    }
  }
}

// ---------------- K4: outputs (512 threads, 2 waves/SIMD) ----------------
// KPl row 32 = zprev (running exclusive cumsum of k', updated from Zpart partials).
#define OUT_LDS_FLOATS (16384 + 8320 + 8580 + 2048 + 2048 + 1056 + 512 + 32)
#define OUT_LDS_BYTES  (OUT_LDS_FLOATS * 4)

__launch_bounds__(512, 2)
__global__ void out_kernel(const float* __restrict__ q_g, const float* __restrict__ k_g,
                           const float* __restrict__ v_g, const float* __restrict__ rf,
                           const unsigned* __restrict__ umax,
                           const float* __restrict__ Sws, const float* __restrict__ Zws,
                           float* __restrict__ out){
  extern __shared__ float sm[];
  float* S_lds = sm;                 // [256][64]
  float* QPl   = S_lds + 16384;      // [32][260]
  float* KPl   = QPl + 8320;         // [33][260] (row 32 = zprev)
  float* Vl    = KPl + 8580;         // [32][64]
  float* QKst  = Vl + 2048;          // [32][64] staging (Q then K)
  float* Al    = QKst + 2048;        // [32][33]
  float* Zpart = Al + 1056;          // [2][256] per-half k' colsum partials
  float* hks   = Zpart + 512;        // [32]

  const int bid = blockIdx.x, t = threadIdx.x;
  const int tm = t & 255, th = t >> 8;    // feature phases: column tm, l-half th
  const int dq = t & 15, lr = t >> 4;     // row lr in [0,32), d-quad dq
  // S-update: thread owns rows [lr*8, lr*8+8) at quad dq

  const float* qb = q_g + (size_t)bid * CHUNK * Dc;
  const float* kb = k_g + (size_t)bid * CHUNK * Dc;
  const float* vb = v_g + (size_t)bid * CHUNK * Dc;

  // prefetch st=0 (one float4 each at 512 threads)
  float4 qr0, kr0, vr0;
  {
    const float4* qs = (const float4*)qb;
    const float4* ks = (const float4*)kb;
    const float4* vs = (const float4*)vb;
    qr0 = qs[t]; kr0 = ks[t]; vr0 = vs[t];
  }

  float rfc[64];
  #pragma unroll
  for (int d = 0; d < 64; ++d) rfc[d] = rf[d*Mc + tm];
  const float kmax = dec_max(umax);

  { // stage S_prev (4096 float4 / 512 threads = 8 each)
    const float4* s4 = (const float4*)(Sws + (size_t)bid*Mc*Dc);
    float4* d4 = (float4*)S_lds;
    #pragma unroll
    for (int r = 0; r < 8; ++r) d4[r*512 + t] = s4[r*512 + t];
  }
  if (t < 256) KPl[32*260 + t] = Zws[(size_t)bid*Mc + t];   // zprev for sub-tile 0
  __syncthreads();

  for (int st = 0; st < 4; ++st){
    { // phase A: write staged Q and V; hks from in-register K
      ((float4*)QKst)[t] = qr0;
      ((float4*)Vl)[t]   = vr0;
      float p0 = kr0.x*kr0.x + kr0.y*kr0.y + kr0.z*kr0.z + kr0.w*kr0.w;
      p0 += __shfl_xor(p0, 8); p0 += __shfl_xor(p0, 4);
      p0 += __shfl_xor(p0, 2); p0 += __shfl_xor(p0, 1);
      if (dq == 0) hks[lr] = -0.5f * S2_ * p0;
    }
    __syncthreads();
    // phase B: q' (half-block th handles rows th*16..th*16+15, column tm)
    if (st < 3){
      const float4* qs = (const float4*)(qb + (st+1)*32*Dc);
      const float4* vs = (const float4*)(vb + (st+1)*32*Dc);
      qr0 = qs[t]; vr0 = vs[t];
    }
    #pragma unroll 1
    for (int l = 0; l < 16; ++l){
      const int ll = th*16 + l;
      float pq = 0.f;
      #pragma unroll
      for (int i = 0; i < 16; ++i){
        float4 qv = ((const float4*)QKst)[ll*16 + i];
        pq += qv.x*rfc[4*i] + qv.y*rfc[4*i+1] + qv.z*rfc[4*i+2] + qv.w*rfc[4*i+3];
      }
      QPl[ll*260 + tm] = NC_ * (__expf(S_SCALE * pq) + EPS_);
    }
    __syncthreads();
    { // phase C: write staged K over QKst; fold previous sub-tile's k' partials into zprev
      ((float4*)QKst)[t] = kr0;
      if (st > 0 && t < 256) KPl[32*260 + t] += Zpart[t] + Zpart[256 + t];
    }
    __syncthreads();
    // phase D: k' (same half split); next K load hides under this
    if (st < 3){
      const float4* ks = (const float4*)(kb + (st+1)*32*Dc);
      kr0 = ks[t];
    }
    {
      float zpart = 0.f;
      #pragma unroll 1
      for (int l = 0; l < 16; ++l){
        const int ll = th*16 + l;
        float pk = 0.f;
        #pragma unroll
        for (int i = 0; i < 16; ++i){
          float4 kv = ((const float4*)QKst)[ll*16 + i];
          pk += kv.x*rfc[4*i] + kv.y*rfc[4*i+1] + kv.z*rfc[4*i+2] + kv.w*rfc[4*i+3];
        }
        float kp = NC_ * (__expf(hks[ll] + S_SCALE*pk - kmax) + EPS_);
        KPl[ll*260 + tm] = kp;
        zpart += kp;
      }
      Zpart[th*256 + tm] = zpart;
    }
    __syncthreads();
    { // phase E: A = Q' K'^T; thread -> row lr, cols {dq, dq+16}
      float a00 = 0.f, a01 = 0.f;
      const float* q0 = &QPl[lr*260];
      const float* k0 = &KPl[dq*260];
      const float* k1 = &KPl[(dq+16)*260];
      #pragma unroll 4
      for (int mq = 0; mq < 64; ++mq){
        const float4 kv0 = *(const float4*)&k0[4*mq];
        const float4 kv1 = *(const float4*)&k1[4*mq];
        const float4 qv0 = *(const float4*)&q0[4*mq];
        a00 += qv0.x*kv0.x + qv0.y*kv0.y + qv0.z*kv0.z + qv0.w*kv0.w;
        a01 += qv0.x*kv1.x + qv0.y*kv1.y + qv0.z*kv1.z + qv0.w*kv1.w;
      }
      Al[lr*33 + dq]      = a00;
      Al[lr*33 + dq + 16] = a01;
    }
    __syncthreads();
    { // phase F: den (in-register) + inter + intra + output store; thread -> (row lr, quad dq)
      // den[lr] = q'_lr . zprev + sum_{j<=lr} A[lr][j]
      float dsum = 0.f;
      {
        const float* qrow = &QPl[lr*260 + dq*16];
        const float* zrow = &KPl[32*260 + dq*16];
        #pragma unroll
        for (int i = 0; i < 4; ++i){
          const float4 qv = *(const float4*)&qrow[4*i];
          const float4 zv = *(const float4*)&zrow[4*i];
          dsum += qv.x*zv.x + qv.y*zv.y + qv.z*zv.z + qv.w*zv.w;
        }
        const float* arow = &Al[lr*33 + dq*2];
        #pragma unroll
        for (int i = 0; i < 2; ++i){
          const int j = dq*2 + i;
          dsum += (j <= lr) ? arow[i] : 0.f;
        }
        dsum += __shfl_xor(dsum, 1);
        dsum += __shfl_xor(dsum, 2);
        dsum += __shfl_xor(dsum, 4);
        dsum += __shfl_xor(dsum, 8);   // all 16 lanes of the row group hold den
      }
      // inter: Q'_lr @ S_prev
      float4 a = make_float4(0.f, 0.f, 0.f, 0.f);
      const float* q0 = &QPl[lr*260];
      #pragma unroll 4
      for (int mb = 0; mb < 64; ++mb){
        const float4 qa = *(const float4*)&q0[4*mb];
        const float4 s0 = *(const float4*)&S_lds[(4*mb  )*64 + 4*dq];
        const float4 s1 = *(const float4*)&S_lds[(4*mb+1)*64 + 4*dq];
        const float4 s2 = *(const float4*)&S_lds[(4*mb+2)*64 + 4*dq];
        const float4 s3 = *(const float4*)&S_lds[(4*mb+3)*64 + 4*dq];
        a.x += qa.x*s0.x + qa.y*s1.x + qa.z*s2.x + qa.w*s3.x;
        a.y += qa.x*s0.y + qa.y*s1.y + qa.z*s2.y + qa.w*s3.y;
        a.z += qa.x*s0.z + qa.y*s1.z + qa.z*s2.z + qa.w*s3.z;
        a.w += qa.x*s0.w + qa.y*s1.w + qa.z*s2.w + qa.w*s3.w;
      }
      // intra: masked A row @ V (wave-uniform trip, per-lane predication)
      {
        const float* arow = &Al[lr*33];
        const int jmax = (lr | 3) + 1;   // uniform within each wave
        #pragma unroll 2
        for (int j = 0; j < jmax; ++j){
          const float av = (j <= lr) ? arow[j] : 0.f;
          const float4 vv = ((const float4*)Vl)[j*16 + dq];
          a.x += av*vv.x; a.y += av*vv.y; a.z += av*vv.z; a.w += av*vv.w;
        }
      }
      // store this sub-tile's output rows immediately
      const float inv = 1.f / dsum;
      a.x *= inv; a.y *= inv; a.z *= inv; a.w *= inv;
      float* ob = out + (size_t)bid * CHUNK * Dc;
      *(float4*)&ob[(st*32 + lr)*Dc + 4*dq] = a;
    }
    __syncthreads();
    { // phase G: S += K'^T V ; thread owns contiguous rows m = lr*8..lr*8+7 at quad dq
      float4 sacc[8];
      #pragma unroll
      for (int mi = 0; mi < 8; ++mi)
        sacc[mi] = *(const float4*)&S_lds[(lr*8 + mi)*64 + 4*dq];
      #pragma unroll 2
      for (int l = 0; l < 32; ++l){
        const float4 vv = ((const float4*)Vl)[l*16 + dq];
        const float* kpr = &KPl[l*260 + lr*8];
        const float4 kpa = *(const float4*)&kpr[0];
        const float4 kpb = *(const float4*)&kpr[4];
        sacc[0].x += kpa.x*vv.x; sacc[0].y += kpa.x*vv.y; sacc[0].z += kpa.x*vv.z; sacc[0].w += kpa.x*vv.w;
        sacc[1].x += kpa.y*vv.x; sacc[1].y += kpa.y*vv.y; sacc[1].z += kpa.y*vv.z; sacc[1].w += kpa.y*vv.w;
        sacc[2].x += kpa.z*vv.x; sacc[2].y += kpa.z*vv.y; sacc[2].z += kpa.z*vv.z; sacc[2].w += kpa.z*vv.w;
        sacc[3].x += kpa.w*vv.x; sacc[3].y += kpa.w*vv.y; sacc[3].z += kpa.w*vv.z; sacc[3].w += kpa.w*vv.w;
        sacc[4].x += kpb.x*vv.x; sacc[4].y += kpb.x*vv.y; sacc[4].z += kpb.x*vv.z; sacc[4].w += kpb.x*vv.w;
        sacc[5].x += kpb.y*vv.x; sacc[5].y += kpb.y*vv.y; sacc[5].z += kpb.y*vv.z; sacc[5].w += kpb.y*vv.w;
        sacc[6].x += kpb.z*vv.x; sacc[6].y += kpb.z*vv.y; sacc[6].z += kpb.z*vv.z; sacc[6].w += kpb.z*vv.w;
        sacc[7].x += kpb.w*vv.x; sacc[7].y += kpb.w*vv.y; sacc[7].z += kpb.w*vv.z; sacc[7].w += kpb.w*vv.w;
      }
      #pragma unroll
      for (int mi = 0; mi < 8; ++mi)
        *(float4*)&S_lds[(lr*8 + mi)*64 + 4*dq] = sacc[mi];
    }
    __syncthreads();
  }
}

extern "C" void kernel_launch(void* const* d_in, const int* in_sizes, int n_in,
                              void* d_out, int out_size, void* d_ws, size_t ws_size,
                              hipStream_t stream){
  const float* q  = (const float*)d_in[0];
  const float* k  = (const float*)d_in[1];
  const float* v  = (const float*)d_in[2];
  const float* rf = (const float*)d_in[3];
  float* out = (float*)d_out;

  unsigned* umax = (unsigned*)d_ws;
  float* Zws = (float*)((char*)d_ws + 1024);                  // 512 KB
  float* Sws = (float*)((char*)d_ws + 1024 + 512*1024);       // 32 MB
  // total ws needed ~ 34.1 MB

  hipMemsetAsync(d_ws, 0, 4, stream);   // umax = encoded identity (below all real h values)
  hmax_kernel <<<256, 256, 0, stream>>>(k, umax);
  chunk_kernel<<<NBLK, 256, 0, stream>>>(k, v, rf, umax, Sws, Zws);
  prefix_kernel<<<NBLK, 256, 0, stream>>>(Sws, Zws);
  hipFuncSetAttribute((const void*)out_kernel,
                      hipFuncAttributeMaxDynamicSharedMemorySize, OUT_LDS_BYTES);
  out_kernel  <<<NBLK, 512, OUT_LDS_BYTES, stream>>>(q, k, v, rf, umax, Sws, Zws, out);
}